// Round 4
// baseline (622.993 us; speedup 1.0000x reference)
//
#include <hip/hip_runtime.h>

// APPNP power iteration: l <- alpha*init + (1-alpha) * A_hat @ l, 5 rounds.
// Round 4: pack (col,val) into one int2 stream -> halves fill_kernel's
// scattered-store line traffic; spmm reads one 8B edge record per nnz.

constexpr float ALPHA  = 0.15f;
constexpr int   NPROP  = 5;
constexpr int   NCLASS = 50;
constexpr int   C2     = 25;   // float2 lanes per node row (50 floats)
constexpr int   NPB    = 10;   // nodes per 256-thread block (250 active)
constexpr int   SCAN_BLOCKS = 256;

// ---------------- CSR build ----------------

__global__ void zero_i32(int* __restrict__ p, int n) {
    int i = blockIdx.x * blockDim.x + threadIdx.x;
    int stride = gridDim.x * blockDim.x;
    for (; i < n; i += stride) p[i] = 0;
}

__global__ void hist_kernel(const int* __restrict__ rows, int* __restrict__ counts, int E) {
    int i = blockIdx.x * blockDim.x + threadIdx.x;
    int stride = gridDim.x * blockDim.x;
    for (; i < E; i += stride) atomicAdd(&counts[rows[i]], 1);
}

// k1: per-block chunk sums
__global__ __launch_bounds__(256) void reduce_chunk(const int* __restrict__ counts,
                                                    int* __restrict__ bs, int n) {
    __shared__ int tsum[256];
    int b = blockIdx.x, t = threadIdx.x;
    int chunk = (n + gridDim.x - 1) / gridDim.x;
    int blo = b * chunk;
    int bhi = blo + chunk; if (bhi > n) bhi = n;
    int s = 0;
    for (int i = blo + t; i < bhi; i += 256) s += counts[i];
    tsum[t] = s;
    __syncthreads();
    for (int off = 128; off; off >>= 1) {
        if (t < off) tsum[t] += tsum[t + off];
        __syncthreads();
    }
    if (t == 0) bs[b] = tsum[0];
}

// k2: exclusive scan of the 256 block sums (single tiny block)
__global__ __launch_bounds__(256) void scan_blocksums(int* __restrict__ bs) {
    __shared__ int tmp[256];
    int t = threadIdx.x;
    tmp[t] = bs[t];
    __syncthreads();
    for (int off = 1; off < 256; off <<= 1) {
        int v = (t >= off) ? tmp[t - off] : 0;
        __syncthreads();
        tmp[t] += v;
        __syncthreads();
    }
    bs[t] = t ? tmp[t - 1] : 0;
}

// k3: per-chunk exclusive prefix with block base -> offs, cursor
__global__ __launch_bounds__(256) void scan_chunk(const int* __restrict__ counts,
                                                  const int* __restrict__ bs,
                                                  int* __restrict__ offs,
                                                  int* __restrict__ cursor,
                                                  int n, int E) {
    __shared__ int tsum[256];
    int b = blockIdx.x, t = threadIdx.x;
    int chunk = (n + gridDim.x - 1) / gridDim.x;
    int blo = b * chunk;
    int bhi = blo + chunk; if (bhi > n) bhi = n;
    int per = (chunk + 255) / 256;
    int lo = blo + t * per;
    int hi = lo + per;
    if (lo > bhi) lo = bhi;
    if (hi > bhi) hi = bhi;
    int s = 0;
    for (int i = lo; i < hi; ++i) s += counts[i];
    tsum[t] = s;
    __syncthreads();
    for (int off = 1; off < 256; off <<= 1) {
        int v = (t >= off) ? tsum[t - off] : 0;
        __syncthreads();
        tsum[t] += v;
        __syncthreads();
    }
    int run = bs[b] + (t ? tsum[t - 1] : 0);
    for (int i = lo; i < hi; ++i) {
        int v = counts[i];
        offs[i] = run;
        cursor[i] = run;
        run += v;
    }
    if (b == 0 && t == 0) offs[n] = E;
}

// fill: one packed 8B store per edge (col,val) -> half the dirtied lines
__global__ void fill_kernel(const int* __restrict__ rows, const int* __restrict__ cols,
                            const float* __restrict__ vals, int* __restrict__ cursor,
                            int2* __restrict__ epack, int E) {
    int i = blockIdx.x * blockDim.x + threadIdx.x;
    int stride = gridDim.x * blockDim.x;
    for (; i < E; i += stride) {
        int r = rows[i];
        int p = atomicAdd(&cursor[r], 1);
        int2 rec;
        rec.x = cols[i];
        rec.y = __float_as_int(vals[i]);
        epack[p] = rec;
    }
}

// ---------------- Fused pull SpMM + combine ----------------

__global__ __launch_bounds__(256) void spmm_kernel(
    const float* __restrict__ l, const float* __restrict__ init,
    const int* __restrict__ offs, const int2* __restrict__ epack,
    float* __restrict__ out, int n) {
    int t = threadIdx.x;
    if (t >= NPB * C2) return;
    int node = blockIdx.x * NPB + t / C2;
    if (node >= n) return;
    int c = t % C2;
    int beg = offs[node], end = offs[node + 1];
    float ax = 0.f, ay = 0.f;
    const float2* l2 = (const float2*)l;
    for (int k = beg; k < end; ++k) {
        int2 e = epack[k];
        int src = e.x;
        float v = __int_as_float(e.y);
        float2 lv = l2[src * C2 + c];
        ax = fmaf(v, lv.x, ax);
        ay = fmaf(v, lv.y, ay);
    }
    float2 iv = ((const float2*)init)[node * C2 + c];
    float2 o;
    o.x = ALPHA * iv.x + (1.0f - ALPHA) * ax;
    o.y = ALPHA * iv.y + (1.0f - ALPHA) * ay;
    ((float2*)out)[node * C2 + c] = o;
}

// ---------------- Fallback (atomic path) ----------------

__global__ void zero_f32(float* __restrict__ p, int n) {
    int i = blockIdx.x * blockDim.x + threadIdx.x;
    int stride = gridDim.x * blockDim.x;
    for (; i < n; i += stride) p[i] = 0.0f;
}

__global__ __launch_bounds__(256) void scatter_kernel(
    const float* __restrict__ l, const int* __restrict__ rows,
    const int* __restrict__ cols, const float* __restrict__ vals,
    float* __restrict__ agg, int E) {
    long long gid = (long long)blockIdx.x * blockDim.x + threadIdx.x;
    int e = (int)(gid >> 6);
    if (e >= E) return;
    int c = (int)(gid & 63);
    if (c >= NCLASS) return;
    float m = vals[e] * l[(long long)cols[e] * NCLASS + c];
    atomicAdd(&agg[(long long)rows[e] * NCLASS + c], m);
}

__global__ void combine_kernel(const float* __restrict__ init,
                               const float* __restrict__ agg,
                               float* __restrict__ out, int n) {
    int i = blockIdx.x * blockDim.x + threadIdx.x;
    int stride = gridDim.x * blockDim.x;
    for (; i < n; i += stride)
        out[i] = ALPHA * init[i] + (1.0f - ALPHA) * agg[i];
}

// ---------------- Launch ----------------

static inline size_t align_up(size_t x, size_t a) { return (x + a - 1) & ~(a - 1); }

extern "C" void kernel_launch(void* const* d_in, const int* in_sizes, int n_in,
                              void* d_out, int out_size, void* d_ws, size_t ws_size,
                              hipStream_t stream) {
    const float* logits = (const float*)d_in[0];
    const int*   rows   = (const int*)d_in[1];
    const int*   cols   = (const int*)d_in[2];
    const float* vals   = (const float*)d_in[3];
    float* out = (float*)d_out;

    const int E  = in_sizes[1];
    const int NC = out_size;
    const int N  = NC / NCLASS;

    // ws layout for CSR path
    size_t off_counts = 0;
    size_t off_offs   = align_up(off_counts + (size_t)N * 4,        256);
    size_t off_cursor = align_up(off_offs   + (size_t)(N + 1) * 4,  256);
    size_t off_bs     = align_up(off_cursor + (size_t)N * 4,        256);
    size_t off_epack  = align_up(off_bs     + (size_t)SCAN_BLOCKS * 4, 256);
    size_t off_lbuf   = align_up(off_epack  + (size_t)E * 8,        256);
    size_t need       = off_lbuf + (size_t)NC * 4;

    if (ws_size >= need) {
        char* ws = (char*)d_ws;
        int*   counts = (int*)  (ws + off_counts);
        int*   offs   = (int*)  (ws + off_offs);
        int*   cursor = (int*)  (ws + off_cursor);
        int*   bs     = (int*)  (ws + off_bs);
        int2*  epack  = (int2*) (ws + off_epack);
        float* lbuf   = (float*)(ws + off_lbuf);

        int eblocks = (E + 255) / 256; if (eblocks > 2048) eblocks = 2048;
        zero_i32<<<(N + 255) / 256, 256, 0, stream>>>(counts, N);
        hist_kernel<<<eblocks, 256, 0, stream>>>(rows, counts, E);
        reduce_chunk<<<SCAN_BLOCKS, 256, 0, stream>>>(counts, bs, N);
        scan_blocksums<<<1, 256, 0, stream>>>(bs);
        scan_chunk<<<SCAN_BLOCKS, 256, 0, stream>>>(counts, bs, offs, cursor, N, E);
        fill_kernel<<<eblocks, 256, 0, stream>>>(rows, cols, vals, cursor, epack, E);

        int sblocks = (N + NPB - 1) / NPB;
        // ping-pong writes: out,lbuf,out,lbuf,out -> final result in d_out
        const float* cur = logits;
        float* dst = out;
        for (int it = 0; it < NPROP; ++it) {
            spmm_kernel<<<sblocks, 256, 0, stream>>>(cur, logits, offs, epack, dst, N);
            cur = dst;
            dst = (dst == out) ? lbuf : out;
        }
    } else {
        // Fallback: atomic scatter path (needs only NC floats of ws)
        float* agg = (float*)d_ws;
        long long sthreads = (long long)E * 64;
        int sblocks = (int)((sthreads + 255) / 256);
        int cblocks = (NC + 255) / 256;
        const float* cur = logits;
        for (int it = 0; it < NPROP; ++it) {
            zero_f32<<<2048, 256, 0, stream>>>(agg, NC);
            scatter_kernel<<<sblocks, 256, 0, stream>>>(cur, rows, cols, vals, agg, E);
            combine_kernel<<<cblocks, 256, 0, stream>>>(logits, agg, out, NC);
            cur = out;
        }
    }
}

// Round 5
// 490.756 us; speedup vs baseline: 1.2695x; 1.2695x over previous
//
#include <hip/hip_runtime.h>

// APPNP power iteration: l <- alpha*init + (1-alpha) * A_hat @ l, 5 rounds.
// Round 5: CSR build via two-pass bucket partition (LDS histograms + localized
// scatters) -- replaces the transaction-bound global hist/fill. Records packed
// as (localrow:9 | col:17, val) in 8B. bucket_csr also emits offs[] directly.

constexpr float ALPHA  = 0.15f;
constexpr int   NPROP  = 5;
constexpr int   NCLASS = 50;
constexpr int   C2     = 25;   // float2 lanes per node row (50 floats)
constexpr int   NPB    = 10;   // nodes per 256-thread block (250 active)
constexpr int   NB     = 256;  // partition buckets
constexpr int   PB     = 256;  // partition blocks
constexpr int   RBSH   = 9;    // rows per bucket = 512

// ---------------- generic two-level scan (n elements, 256 blocks) ----------

__global__ __launch_bounds__(256) void reduce_chunk(const int* __restrict__ counts,
                                                    int* __restrict__ bs, int n) {
    __shared__ int tsum[256];
    int b = blockIdx.x, t = threadIdx.x;
    int chunk = (n + gridDim.x - 1) / gridDim.x;
    int blo = b * chunk;
    int bhi = blo + chunk; if (bhi > n) bhi = n;
    int s = 0;
    for (int i = blo + t; i < bhi; i += 256) s += counts[i];
    tsum[t] = s;
    __syncthreads();
    for (int off = 128; off; off >>= 1) {
        if (t < off) tsum[t] += tsum[t + off];
        __syncthreads();
    }
    if (t == 0) bs[b] = tsum[0];
}

__global__ __launch_bounds__(256) void scan_blocksums(int* __restrict__ bs) {
    __shared__ int tmp[256];
    int t = threadIdx.x;
    tmp[t] = bs[t];
    __syncthreads();
    for (int off = 1; off < 256; off <<= 1) {
        int v = (t >= off) ? tmp[t - off] : 0;
        __syncthreads();
        tmp[t] += v;
        __syncthreads();
    }
    bs[t] = t ? tmp[t - 1] : 0;
}

// exclusive scan; in-place safe (outs may alias counts)
__global__ __launch_bounds__(256) void scan_chunk(int* __restrict__ counts,
                                                  const int* __restrict__ bs,
                                                  int* __restrict__ offs,
                                                  int n, int E) {
    __shared__ int tsum[256];
    int b = blockIdx.x, t = threadIdx.x;
    int chunk = (n + gridDim.x - 1) / gridDim.x;
    int blo = b * chunk;
    int bhi = blo + chunk; if (bhi > n) bhi = n;
    int per = (chunk + 255) / 256;
    int lo = blo + t * per;
    int hi = lo + per;
    if (lo > bhi) lo = bhi;
    if (hi > bhi) hi = bhi;
    int s = 0;
    for (int i = lo; i < hi; ++i) s += counts[i];
    tsum[t] = s;
    __syncthreads();
    for (int off = 1; off < 256; off <<= 1) {
        int v = (t >= off) ? tsum[t - off] : 0;
        __syncthreads();
        tsum[t] += v;
        __syncthreads();
    }
    int run = bs[b] + (t ? tsum[t - 1] : 0);
    for (int i = lo; i < hi; ++i) {
        int v = counts[i];
        offs[i] = run;
        run += v;
    }
    if (b == 0 && t == 0) offs[n] = E;
}

// ---------------- bucket partition ----------------

// per-block LDS histogram over NB buckets -> blockhist[bucket*PB + block]
__global__ __launch_bounds__(256) void part_hist(const int* __restrict__ rows,
                                                 int* __restrict__ blockhist, int E) {
    __shared__ int h[NB];
    int b = blockIdx.x, t = threadIdx.x;
    h[t] = 0;
    __syncthreads();
    int chunk = (E + gridDim.x - 1) / gridDim.x;
    int lo = b * chunk;
    int hi = lo + chunk; if (hi > E) hi = E;
    for (int i = lo + t; i < hi; i += 256) atomicAdd(&h[rows[i] >> RBSH], 1);
    __syncthreads();
    blockhist[t * PB + b] = h[t];
}

// scatter packed records into per-(bucket,block) reserved runs
__global__ __launch_bounds__(256) void part_scatter(const int* __restrict__ rows,
                                                    const int* __restrict__ cols,
                                                    const float* __restrict__ vals,
                                                    const int* __restrict__ bh_scanned,
                                                    int2* __restrict__ recbuf, int E) {
    __shared__ int cur[NB];
    int b = blockIdx.x, t = threadIdx.x;
    cur[t] = bh_scanned[t * PB + b];
    __syncthreads();
    int chunk = (E + gridDim.x - 1) / gridDim.x;
    int lo = b * chunk;
    int hi = lo + chunk; if (hi > E) hi = E;
    for (int i = lo + t; i < hi; i += 256) {
        int r  = rows[i];
        int bk = r >> RBSH;
        int p  = atomicAdd(&cur[bk], 1);
        int2 rec;
        rec.x = ((r & ((1 << RBSH) - 1)) << 17) | cols[i];
        rec.y = __float_as_int(vals[i]);
        recbuf[p] = rec;
    }
}

// one block per bucket: LDS count + scan -> offs, then scatter epack within
// the bucket's contiguous (L2-hot) output window.
__global__ __launch_bounds__(256) void bucket_csr(const int2* __restrict__ recbuf,
                                                  const int* __restrict__ bh_scanned,
                                                  int* __restrict__ offs,
                                                  int2* __restrict__ epack,
                                                  int N, int E) {
    __shared__ int cnt[512];
    __shared__ int ex[512];
    __shared__ int pair[256];
    int b = blockIdx.x, t = threadIdx.x;
    int rowlo = b << RBSH;
    int nrows = N - rowlo; if (nrows > (1 << RBSH)) nrows = (1 << RBSH);
    int bstart = bh_scanned[b * PB];
    int bend   = (b == gridDim.x - 1) ? E : bh_scanned[(b + 1) * PB];

    cnt[t] = 0; cnt[t + 256] = 0;
    __syncthreads();
    for (int k = bstart + t; k < bend; k += 256)
        atomicAdd(&cnt[recbuf[k].x >> 17], 1);
    __syncthreads();

    // exclusive scan of cnt[0..512) with 256 threads (pair-sum + Hillis-Steele)
    int c0 = cnt[2 * t], c1 = cnt[2 * t + 1];
    pair[t] = c0 + c1;
    __syncthreads();
    for (int off = 1; off < 256; off <<= 1) {
        int v = (t >= off) ? pair[t - off] : 0;
        __syncthreads();
        pair[t] += v;
        __syncthreads();
    }
    int pbase = t ? pair[t - 1] : 0;
    ex[2 * t]     = pbase;
    ex[2 * t + 1] = pbase + c0;
    __syncthreads();

    // emit offs for this bucket's rows
    if (t < nrows)        offs[rowlo + t]       = bstart + ex[t];
    if (t + 256 < nrows)  offs[rowlo + t + 256] = bstart + ex[t + 256];
    if (t == 0 && rowlo + nrows == N) offs[N] = E;

    // scatter to final CSR positions (ex doubles as cursor)
    for (int k = bstart + t; k < bend; k += 256) {
        int2 rec = recbuf[k];
        int lr  = rec.x >> 17;
        int col = rec.x & 0x1FFFF;
        int p   = bstart + atomicAdd(&ex[lr], 1);
        int2 e; e.x = col; e.y = rec.y;
        epack[p] = e;
    }
}

// ---------------- Fused pull SpMM + combine ----------------

__global__ __launch_bounds__(256) void spmm_kernel(
    const float* __restrict__ l, const float* __restrict__ init,
    const int* __restrict__ offs, const int2* __restrict__ epack,
    float* __restrict__ out, int n) {
    int t = threadIdx.x;
    if (t >= NPB * C2) return;
    int node = blockIdx.x * NPB + t / C2;
    if (node >= n) return;
    int c = t % C2;
    int beg = offs[node], end = offs[node + 1];
    float ax = 0.f, ay = 0.f;
    const float2* l2 = (const float2*)l;
    for (int k = beg; k < end; ++k) {
        int2 e = epack[k];
        int src = e.x;
        float v = __int_as_float(e.y);
        float2 lv = l2[src * C2 + c];
        ax = fmaf(v, lv.x, ax);
        ay = fmaf(v, lv.y, ay);
    }
    float2 iv = ((const float2*)init)[node * C2 + c];
    float2 o;
    o.x = ALPHA * iv.x + (1.0f - ALPHA) * ax;
    o.y = ALPHA * iv.y + (1.0f - ALPHA) * ay;
    ((float2*)out)[node * C2 + c] = o;
}

// ---------------- Fallback (atomic path) ----------------

__global__ void zero_f32(float* __restrict__ p, int n) {
    int i = blockIdx.x * blockDim.x + threadIdx.x;
    int stride = gridDim.x * blockDim.x;
    for (; i < n; i += stride) p[i] = 0.0f;
}

__global__ __launch_bounds__(256) void scatter_kernel(
    const float* __restrict__ l, const int* __restrict__ rows,
    const int* __restrict__ cols, const float* __restrict__ vals,
    float* __restrict__ agg, int E) {
    long long gid = (long long)blockIdx.x * blockDim.x + threadIdx.x;
    int e = (int)(gid >> 6);
    if (e >= E) return;
    int c = (int)(gid & 63);
    if (c >= NCLASS) return;
    float m = vals[e] * l[(long long)cols[e] * NCLASS + c];
    atomicAdd(&agg[(long long)rows[e] * NCLASS + c], m);
}

__global__ void combine_kernel(const float* __restrict__ init,
                               const float* __restrict__ agg,
                               float* __restrict__ out, int n) {
    int i = blockIdx.x * blockDim.x + threadIdx.x;
    int stride = gridDim.x * blockDim.x;
    for (; i < n; i += stride)
        out[i] = ALPHA * init[i] + (1.0f - ALPHA) * agg[i];
}

// ---------------- Launch ----------------

static inline size_t align_up(size_t x, size_t a) { return (x + a - 1) & ~(a - 1); }

extern "C" void kernel_launch(void* const* d_in, const int* in_sizes, int n_in,
                              void* d_out, int out_size, void* d_ws, size_t ws_size,
                              hipStream_t stream) {
    const float* logits = (const float*)d_in[0];
    const int*   rows   = (const int*)d_in[1];
    const int*   cols   = (const int*)d_in[2];
    const float* vals   = (const float*)d_in[3];
    float* out = (float*)d_out;

    const int E  = in_sizes[1];
    const int NC = out_size;
    const int N  = NC / NCLASS;

    const int NBPB = NB * PB;                 // blockhist scan length

    size_t off_bh     = 0;
    size_t off_bs     = align_up(off_bh   + (size_t)(NBPB + 1) * 4, 256);
    size_t off_offs   = align_up(off_bs   + (size_t)256 * 4,        256);
    size_t off_recbuf = align_up(off_offs + (size_t)(N + 1) * 4,    256);
    size_t off_epack  = align_up(off_recbuf + (size_t)E * 8,        256);
    size_t off_lbuf   = align_up(off_epack  + (size_t)E * 8,        256);
    size_t need       = off_lbuf + (size_t)NC * 4;

    bool fits = (N <= (NB << RBSH)) && (N <= (1 << 17)) && (ws_size >= need);

    if (fits) {
        char* ws = (char*)d_ws;
        int*   bh     = (int*)  (ws + off_bh);
        int*   bs     = (int*)  (ws + off_bs);
        int*   offs   = (int*)  (ws + off_offs);
        int2*  recbuf = (int2*) (ws + off_recbuf);
        int2*  epack  = (int2*) (ws + off_epack);
        float* lbuf   = (float*)(ws + off_lbuf);

        int nbuckets = (N + (1 << RBSH) - 1) >> RBSH;

        part_hist<<<PB, 256, 0, stream>>>(rows, bh, E);
        reduce_chunk<<<256, 256, 0, stream>>>(bh, bs, NBPB);
        scan_blocksums<<<1, 256, 0, stream>>>(bs);
        scan_chunk<<<256, 256, 0, stream>>>(bh, bs, bh, NBPB, E);
        part_scatter<<<PB, 256, 0, stream>>>(rows, cols, vals, bh, recbuf, E);
        bucket_csr<<<nbuckets, 256, 0, stream>>>(recbuf, bh, offs, epack, N, E);

        int sblocks = (N + NPB - 1) / NPB;
        // ping-pong writes: out,lbuf,out,lbuf,out -> final result in d_out
        const float* cur = logits;
        float* dst = out;
        for (int it = 0; it < NPROP; ++it) {
            spmm_kernel<<<sblocks, 256, 0, stream>>>(cur, logits, offs, epack, dst, N);
            cur = dst;
            dst = (dst == out) ? lbuf : out;
        }
    } else {
        // Fallback: atomic scatter path (needs only NC floats of ws)
        float* agg = (float*)d_ws;
        long long sthreads = (long long)E * 64;
        int sblocks = (int)((sthreads + 255) / 256);
        int cblocks = (NC + 255) / 256;
        const float* cur = logits;
        for (int it = 0; it < NPROP; ++it) {
            zero_f32<<<2048, 256, 0, stream>>>(agg, NC);
            scatter_kernel<<<sblocks, 256, 0, stream>>>(cur, rows, cols, vals, agg, E);
            combine_kernel<<<cblocks, 256, 0, stream>>>(logits, agg, out, NC);
            cur = out;
        }
    }
}

// Round 6
// 314.528 us; speedup vs baseline: 1.9807x; 1.5603x over previous
//
#include <hip/hip_runtime.h>

// APPNP power iteration: l <- alpha*init + (1-alpha) * A_hat @ l, 5 rounds.
// Round 6: gather operand kept in bf16 with 128B-padded rows (exactly 2
// sectors per edge gather vs ~4 for unpadded f32) + edge-loop unroll x2 for
// 2 independent gather chains in flight. init term stays f32; final iteration
// writes f32 directly to d_out. lbf_b aliases the dead-after-build recbuf.

constexpr float ALPHA  = 0.15f;
constexpr int   NPROP  = 5;
constexpr int   NCLASS = 50;
constexpr int   C2     = 25;   // float2 lanes per node row (50 floats)
constexpr int   C2P    = 32;   // padded row stride in uints (128 B)
constexpr int   NPB    = 10;   // nodes per 256-thread block (250 active)
constexpr int   NB     = 256;  // partition buckets
constexpr int   PB     = 256;  // partition blocks
constexpr int   RBSH   = 9;    // rows per bucket = 512

__device__ __forceinline__ unsigned f2bf(float x) {
    unsigned u = __float_as_uint(x);
    return (u + 0x7fffu + ((u >> 16) & 1u)) >> 16;   // RNE
}

// ---------------- generic two-level scan (n elements, 256 blocks) ----------

__global__ __launch_bounds__(256) void reduce_chunk(const int* __restrict__ counts,
                                                    int* __restrict__ bs, int n) {
    __shared__ int tsum[256];
    int b = blockIdx.x, t = threadIdx.x;
    int chunk = (n + gridDim.x - 1) / gridDim.x;
    int blo = b * chunk;
    int bhi = blo + chunk; if (bhi > n) bhi = n;
    int s = 0;
    for (int i = blo + t; i < bhi; i += 256) s += counts[i];
    tsum[t] = s;
    __syncthreads();
    for (int off = 128; off; off >>= 1) {
        if (t < off) tsum[t] += tsum[t + off];
        __syncthreads();
    }
    if (t == 0) bs[b] = tsum[0];
}

__global__ __launch_bounds__(256) void scan_blocksums(int* __restrict__ bs) {
    __shared__ int tmp[256];
    int t = threadIdx.x;
    tmp[t] = bs[t];
    __syncthreads();
    for (int off = 1; off < 256; off <<= 1) {
        int v = (t >= off) ? tmp[t - off] : 0;
        __syncthreads();
        tmp[t] += v;
        __syncthreads();
    }
    bs[t] = t ? tmp[t - 1] : 0;
}

__global__ __launch_bounds__(256) void scan_chunk(int* __restrict__ counts,
                                                  const int* __restrict__ bs,
                                                  int* __restrict__ offs,
                                                  int n, int E) {
    __shared__ int tsum[256];
    int b = blockIdx.x, t = threadIdx.x;
    int chunk = (n + gridDim.x - 1) / gridDim.x;
    int blo = b * chunk;
    int bhi = blo + chunk; if (bhi > n) bhi = n;
    int per = (chunk + 255) / 256;
    int lo = blo + t * per;
    int hi = lo + per;
    if (lo > bhi) lo = bhi;
    if (hi > bhi) hi = bhi;
    int s = 0;
    for (int i = lo; i < hi; ++i) s += counts[i];
    tsum[t] = s;
    __syncthreads();
    for (int off = 1; off < 256; off <<= 1) {
        int v = (t >= off) ? tsum[t - off] : 0;
        __syncthreads();
        tsum[t] += v;
        __syncthreads();
    }
    int run = bs[b] + (t ? tsum[t - 1] : 0);
    for (int i = lo; i < hi; ++i) {
        int v = counts[i];
        offs[i] = run;
        run += v;
    }
    if (b == 0 && t == 0) offs[n] = E;
}

// ---------------- bucket partition ----------------

__global__ __launch_bounds__(256) void part_hist(const int* __restrict__ rows,
                                                 int* __restrict__ blockhist, int E) {
    __shared__ int h[NB];
    int b = blockIdx.x, t = threadIdx.x;
    h[t] = 0;
    __syncthreads();
    int chunk = (E + gridDim.x - 1) / gridDim.x;
    int lo = b * chunk;
    int hi = lo + chunk; if (hi > E) hi = E;
    for (int i = lo + t; i < hi; i += 256) atomicAdd(&h[rows[i] >> RBSH], 1);
    __syncthreads();
    blockhist[t * PB + b] = h[t];
}

__global__ __launch_bounds__(256) void part_scatter(const int* __restrict__ rows,
                                                    const int* __restrict__ cols,
                                                    const float* __restrict__ vals,
                                                    const int* __restrict__ bh_scanned,
                                                    int2* __restrict__ recbuf, int E) {
    __shared__ int cur[NB];
    int b = blockIdx.x, t = threadIdx.x;
    cur[t] = bh_scanned[t * PB + b];
    __syncthreads();
    int chunk = (E + gridDim.x - 1) / gridDim.x;
    int lo = b * chunk;
    int hi = lo + chunk; if (hi > E) hi = E;
    for (int i = lo + t; i < hi; i += 256) {
        int r  = rows[i];
        int bk = r >> RBSH;
        int p  = atomicAdd(&cur[bk], 1);
        int2 rec;
        rec.x = ((r & ((1 << RBSH) - 1)) << 17) | cols[i];
        rec.y = __float_as_int(vals[i]);
        recbuf[p] = rec;
    }
}

__global__ __launch_bounds__(256) void bucket_csr(const int2* __restrict__ recbuf,
                                                  const int* __restrict__ bh_scanned,
                                                  int* __restrict__ offs,
                                                  int2* __restrict__ epack,
                                                  int N, int E) {
    __shared__ int cnt[512];
    __shared__ int ex[512];
    __shared__ int pair[256];
    int b = blockIdx.x, t = threadIdx.x;
    int rowlo = b << RBSH;
    int nrows = N - rowlo; if (nrows > (1 << RBSH)) nrows = (1 << RBSH);
    int bstart = bh_scanned[b * PB];
    int bend   = (b == gridDim.x - 1) ? E : bh_scanned[(b + 1) * PB];

    cnt[t] = 0; cnt[t + 256] = 0;
    __syncthreads();
    for (int k = bstart + t; k < bend; k += 256)
        atomicAdd(&cnt[recbuf[k].x >> 17], 1);
    __syncthreads();

    int c0 = cnt[2 * t], c1 = cnt[2 * t + 1];
    pair[t] = c0 + c1;
    __syncthreads();
    for (int off = 1; off < 256; off <<= 1) {
        int v = (t >= off) ? pair[t - off] : 0;
        __syncthreads();
        pair[t] += v;
        __syncthreads();
    }
    int pbase = t ? pair[t - 1] : 0;
    ex[2 * t]     = pbase;
    ex[2 * t + 1] = pbase + c0;
    __syncthreads();

    if (t < nrows)        offs[rowlo + t]       = bstart + ex[t];
    if (t + 256 < nrows)  offs[rowlo + t + 256] = bstart + ex[t + 256];
    if (t == 0 && rowlo + nrows == N) offs[N] = E;

    for (int k = bstart + t; k < bend; k += 256) {
        int2 rec = recbuf[k];
        int lr  = rec.x >> 17;
        int col = rec.x & 0x1FFFF;
        int p   = bstart + atomicAdd(&ex[lr], 1);
        int2 e; e.x = col; e.y = rec.y;
        epack[p] = e;
    }
}

// ---------------- bf16 conversion of logits (padded rows) ----------------

__global__ __launch_bounds__(256) void to_bf16_kernel(const float* __restrict__ logits,
                                                      unsigned* __restrict__ lbf, int N) {
    int i = blockIdx.x * blockDim.x + threadIdx.x;
    int stride = gridDim.x * blockDim.x;
    int total = N << 5;            // N * C2P
    const float2* l2 = (const float2*)logits;
    for (; i < total; i += stride) {
        int node = i >> 5;
        int c = i & 31;
        unsigned v = 0;
        if (c < C2) {
            float2 lv = l2[node * C2 + c];
            v = f2bf(lv.x) | (f2bf(lv.y) << 16);
        }
        lbf[i] = v;
    }
}

// ---------------- Fused pull SpMM + combine (bf16 gather) ----------------

__global__ __launch_bounds__(256) void spmm_bf_kernel(
    const unsigned* __restrict__ lbf, const float* __restrict__ init,
    const int* __restrict__ offs, const int2* __restrict__ epack,
    unsigned* __restrict__ obf, float* __restrict__ of32, int n, int final_f32) {
    int t = threadIdx.x;
    if (t >= NPB * C2) return;
    int node = blockIdx.x * NPB + t / C2;
    if (node >= n) return;
    int c = t % C2;
    int beg = offs[node], end = offs[node + 1];
    float ax = 0.f, ay = 0.f;
    int k = beg;
    for (; k + 2 <= end; k += 2) {
        int2 e0 = epack[k];
        int2 e1 = epack[k + 1];
        unsigned u0 = lbf[(e0.x << 5) + c];
        unsigned u1 = lbf[(e1.x << 5) + c];
        float v0 = __int_as_float(e0.y);
        float v1 = __int_as_float(e1.y);
        ax = fmaf(v0, __uint_as_float(u0 << 16), ax);
        ay = fmaf(v0, __uint_as_float(u0 & 0xffff0000u), ay);
        ax = fmaf(v1, __uint_as_float(u1 << 16), ax);
        ay = fmaf(v1, __uint_as_float(u1 & 0xffff0000u), ay);
    }
    if (k < end) {
        int2 e = epack[k];
        unsigned u = lbf[(e.x << 5) + c];
        float v = __int_as_float(e.y);
        ax = fmaf(v, __uint_as_float(u << 16), ax);
        ay = fmaf(v, __uint_as_float(u & 0xffff0000u), ay);
    }
    float2 iv = ((const float2*)init)[node * C2 + c];
    float ox = ALPHA * iv.x + (1.0f - ALPHA) * ax;
    float oy = ALPHA * iv.y + (1.0f - ALPHA) * ay;
    if (final_f32) {
        float2 o; o.x = ox; o.y = oy;
        ((float2*)of32)[node * C2 + c] = o;
    } else {
        obf[(node << 5) + c] = f2bf(ox) | (f2bf(oy) << 16);
    }
}

// ---------------- Fallback (atomic path) ----------------

__global__ void zero_f32(float* __restrict__ p, int n) {
    int i = blockIdx.x * blockDim.x + threadIdx.x;
    int stride = gridDim.x * blockDim.x;
    for (; i < n; i += stride) p[i] = 0.0f;
}

__global__ __launch_bounds__(256) void scatter_kernel(
    const float* __restrict__ l, const int* __restrict__ rows,
    const int* __restrict__ cols, const float* __restrict__ vals,
    float* __restrict__ agg, int E) {
    long long gid = (long long)blockIdx.x * blockDim.x + threadIdx.x;
    int e = (int)(gid >> 6);
    if (e >= E) return;
    int c = (int)(gid & 63);
    if (c >= NCLASS) return;
    float m = vals[e] * l[(long long)cols[e] * NCLASS + c];
    atomicAdd(&agg[(long long)rows[e] * NCLASS + c], m);
}

__global__ void combine_kernel(const float* __restrict__ init,
                               const float* __restrict__ agg,
                               float* __restrict__ out, int n) {
    int i = blockIdx.x * blockDim.x + threadIdx.x;
    int stride = gridDim.x * blockDim.x;
    for (; i < n; i += stride)
        out[i] = ALPHA * init[i] + (1.0f - ALPHA) * agg[i];
}

// ---------------- Launch ----------------

static inline size_t align_up(size_t x, size_t a) { return (x + a - 1) & ~(a - 1); }

extern "C" void kernel_launch(void* const* d_in, const int* in_sizes, int n_in,
                              void* d_out, int out_size, void* d_ws, size_t ws_size,
                              hipStream_t stream) {
    const float* logits = (const float*)d_in[0];
    const int*   rows   = (const int*)d_in[1];
    const int*   cols   = (const int*)d_in[2];
    const float* vals   = (const float*)d_in[3];
    float* out = (float*)d_out;

    const int E  = in_sizes[1];
    const int NC = out_size;
    const int N  = NC / NCLASS;

    const int NBPB = NB * PB;

    // ws layout; lbf_b aliases recbuf (recbuf dead after bucket_csr,
    // lbf_b first written by spmm iteration 0 which runs after it).
    size_t rec_bytes  = (size_t)E * 8;
    size_t lbf_bytes  = (size_t)N * C2P * 4;
    size_t shared_sz  = rec_bytes > lbf_bytes ? rec_bytes : lbf_bytes;

    size_t off_bh     = 0;
    size_t off_bs     = align_up(off_bh   + (size_t)(NBPB + 1) * 4, 256);
    size_t off_offs   = align_up(off_bs   + (size_t)256 * 4,        256);
    size_t off_shared = align_up(off_offs + (size_t)(N + 1) * 4,    256);
    size_t off_epack  = align_up(off_shared + shared_sz,            256);
    size_t off_lbfa   = align_up(off_epack  + (size_t)E * 8,        256);
    size_t need       = off_lbfa + lbf_bytes;

    bool fits = (N <= (NB << RBSH)) && (N <= (1 << 17)) && (ws_size >= need);

    if (fits) {
        char* ws = (char*)d_ws;
        int*      bh     = (int*)     (ws + off_bh);
        int*      bs     = (int*)     (ws + off_bs);
        int*      offs   = (int*)     (ws + off_offs);
        int2*     recbuf = (int2*)    (ws + off_shared);
        unsigned* lbf_b  = (unsigned*)(ws + off_shared);
        int2*     epack  = (int2*)    (ws + off_epack);
        unsigned* lbf_a  = (unsigned*)(ws + off_lbfa);

        int nbuckets = (N + (1 << RBSH) - 1) >> RBSH;

        part_hist<<<PB, 256, 0, stream>>>(rows, bh, E);
        reduce_chunk<<<256, 256, 0, stream>>>(bh, bs, NBPB);
        scan_blocksums<<<1, 256, 0, stream>>>(bs);
        scan_chunk<<<256, 256, 0, stream>>>(bh, bs, bh, NBPB, E);
        part_scatter<<<PB, 256, 0, stream>>>(rows, cols, vals, bh, recbuf, E);
        bucket_csr<<<nbuckets, 256, 0, stream>>>(recbuf, bh, offs, epack, N, E);
        to_bf16_kernel<<<2048, 256, 0, stream>>>(logits, lbf_a, N);

        int sblocks = (N + NPB - 1) / NPB;
        // ping-pong: a->b, b->a, a->b, b->a, a->d_out(f32)
        unsigned* cur = lbf_a;
        unsigned* nxt = lbf_b;
        for (int it = 0; it < NPROP; ++it) {
            int fin = (it == NPROP - 1);
            spmm_bf_kernel<<<sblocks, 256, 0, stream>>>(
                cur, logits, offs, epack, nxt, out, N, fin);
            unsigned* tmp = cur; cur = nxt; nxt = tmp;
        }
    } else {
        // Fallback: atomic scatter path (needs only NC floats of ws)
        float* agg = (float*)d_ws;
        long long sthreads = (long long)E * 64;
        int sblocks = (int)((sthreads + 255) / 256);
        int cblocks = (NC + 255) / 256;
        const float* cur = logits;
        for (int it = 0; it < NPROP; ++it) {
            zero_f32<<<2048, 256, 0, stream>>>(agg, NC);
            scatter_kernel<<<sblocks, 256, 0, stream>>>(cur, rows, cols, vals, agg, E);
            combine_kernel<<<cblocks, 256, 0, stream>>>(logits, agg, out, NC);
            cur = out;
        }
    }
}

// Round 11
// 273.305 us; speedup vs baseline: 2.2795x; 1.1508x over previous
//
#include <hip/hip_runtime.h>

// APPNP power iteration: l <- alpha*init + (1-alpha) * A_hat @ l, 5 rounds.
// Round 11 = round 7 resubmitted (4x infra failure on same container, no
// data): spmm edge-loop unroll x4 (4 independent gather chains in flight,
// 2 accumulator pairs) -- attacks the latency-bound gather (VALUBusy 24%,
// 2.3 TB/s of 6.3 achievable at round 6). Everything else unchanged.

constexpr float ALPHA  = 0.15f;
constexpr int   NPROP  = 5;
constexpr int   NCLASS = 50;
constexpr int   C2     = 25;   // float2 lanes per node row (50 floats)
constexpr int   C2P    = 32;   // padded row stride in uints (128 B)
constexpr int   NPB    = 10;   // nodes per 256-thread block (250 active)
constexpr int   NB     = 256;  // partition buckets
constexpr int   PB     = 256;  // partition blocks
constexpr int   RBSH   = 9;    // rows per bucket = 512

__device__ __forceinline__ unsigned f2bf(float x) {
    unsigned u = __float_as_uint(x);
    return (u + 0x7fffu + ((u >> 16) & 1u)) >> 16;   // RNE
}

// ---------------- generic two-level scan (n elements, 256 blocks) ----------

__global__ __launch_bounds__(256) void reduce_chunk(const int* __restrict__ counts,
                                                    int* __restrict__ bs, int n) {
    __shared__ int tsum[256];
    int b = blockIdx.x, t = threadIdx.x;
    int chunk = (n + gridDim.x - 1) / gridDim.x;
    int blo = b * chunk;
    int bhi = blo + chunk; if (bhi > n) bhi = n;
    int s = 0;
    for (int i = blo + t; i < bhi; i += 256) s += counts[i];
    tsum[t] = s;
    __syncthreads();
    for (int off = 128; off; off >>= 1) {
        if (t < off) tsum[t] += tsum[t + off];
        __syncthreads();
    }
    if (t == 0) bs[b] = tsum[0];
}

__global__ __launch_bounds__(256) void scan_blocksums(int* __restrict__ bs) {
    __shared__ int tmp[256];
    int t = threadIdx.x;
    tmp[t] = bs[t];
    __syncthreads();
    for (int off = 1; off < 256; off <<= 1) {
        int v = (t >= off) ? tmp[t - off] : 0;
        __syncthreads();
        tmp[t] += v;
        __syncthreads();
    }
    bs[t] = t ? tmp[t - 1] : 0;
}

__global__ __launch_bounds__(256) void scan_chunk(int* __restrict__ counts,
                                                  const int* __restrict__ bs,
                                                  int* __restrict__ offs,
                                                  int n, int E) {
    __shared__ int tsum[256];
    int b = blockIdx.x, t = threadIdx.x;
    int chunk = (n + gridDim.x - 1) / gridDim.x;
    int blo = b * chunk;
    int bhi = blo + chunk; if (bhi > n) bhi = n;
    int per = (chunk + 255) / 256;
    int lo = blo + t * per;
    int hi = lo + per;
    if (lo > bhi) lo = bhi;
    if (hi > bhi) hi = bhi;
    int s = 0;
    for (int i = lo; i < hi; ++i) s += counts[i];
    tsum[t] = s;
    __syncthreads();
    for (int off = 1; off < 256; off <<= 1) {
        int v = (t >= off) ? tsum[t - off] : 0;
        __syncthreads();
        tsum[t] += v;
        __syncthreads();
    }
    int run = bs[b] + (t ? tsum[t - 1] : 0);
    for (int i = lo; i < hi; ++i) {
        int v = counts[i];
        offs[i] = run;
        run += v;
    }
    if (b == 0 && t == 0) offs[n] = E;
}

// ---------------- bucket partition ----------------

__global__ __launch_bounds__(256) void part_hist(const int* __restrict__ rows,
                                                 int* __restrict__ blockhist, int E) {
    __shared__ int h[NB];
    int b = blockIdx.x, t = threadIdx.x;
    h[t] = 0;
    __syncthreads();
    int chunk = (E + gridDim.x - 1) / gridDim.x;
    int lo = b * chunk;
    int hi = lo + chunk; if (hi > E) hi = E;
    for (int i = lo + t; i < hi; i += 256) atomicAdd(&h[rows[i] >> RBSH], 1);
    __syncthreads();
    blockhist[t * PB + b] = h[t];
}

__global__ __launch_bounds__(256) void part_scatter(const int* __restrict__ rows,
                                                    const int* __restrict__ cols,
                                                    const float* __restrict__ vals,
                                                    const int* __restrict__ bh_scanned,
                                                    int2* __restrict__ recbuf, int E) {
    __shared__ int cur[NB];
    int b = blockIdx.x, t = threadIdx.x;
    cur[t] = bh_scanned[t * PB + b];
    __syncthreads();
    int chunk = (E + gridDim.x - 1) / gridDim.x;
    int lo = b * chunk;
    int hi = lo + chunk; if (hi > E) hi = E;
    for (int i = lo + t; i < hi; i += 256) {
        int r  = rows[i];
        int bk = r >> RBSH;
        int p  = atomicAdd(&cur[bk], 1);
        int2 rec;
        rec.x = ((r & ((1 << RBSH) - 1)) << 17) | cols[i];
        rec.y = __float_as_int(vals[i]);
        recbuf[p] = rec;
    }
}

__global__ __launch_bounds__(256) void bucket_csr(const int2* __restrict__ recbuf,
                                                  const int* __restrict__ bh_scanned,
                                                  int* __restrict__ offs,
                                                  int2* __restrict__ epack,
                                                  int N, int E) {
    __shared__ int cnt[512];
    __shared__ int ex[512];
    __shared__ int pair[256];
    int b = blockIdx.x, t = threadIdx.x;
    int rowlo = b << RBSH;
    int nrows = N - rowlo; if (nrows > (1 << RBSH)) nrows = (1 << RBSH);
    int bstart = bh_scanned[b * PB];
    int bend   = (b == gridDim.x - 1) ? E : bh_scanned[(b + 1) * PB];

    cnt[t] = 0; cnt[t + 256] = 0;
    __syncthreads();
    for (int k = bstart + t; k < bend; k += 256)
        atomicAdd(&cnt[recbuf[k].x >> 17], 1);
    __syncthreads();

    int c0 = cnt[2 * t], c1 = cnt[2 * t + 1];
    pair[t] = c0 + c1;
    __syncthreads();
    for (int off = 1; off < 256; off <<= 1) {
        int v = (t >= off) ? pair[t - off] : 0;
        __syncthreads();
        pair[t] += v;
        __syncthreads();
    }
    int pbase = t ? pair[t - 1] : 0;
    ex[2 * t]     = pbase;
    ex[2 * t + 1] = pbase + c0;
    __syncthreads();

    if (t < nrows)        offs[rowlo + t]       = bstart + ex[t];
    if (t + 256 < nrows)  offs[rowlo + t + 256] = bstart + ex[t + 256];
    if (t == 0 && rowlo + nrows == N) offs[N] = E;

    for (int k = bstart + t; k < bend; k += 256) {
        int2 rec = recbuf[k];
        int lr  = rec.x >> 17;
        int col = rec.x & 0x1FFFF;
        int p   = bstart + atomicAdd(&ex[lr], 1);
        int2 e; e.x = col; e.y = rec.y;
        epack[p] = e;
    }
}

// ---------------- bf16 conversion of logits (padded rows) ----------------

__global__ __launch_bounds__(256) void to_bf16_kernel(const float* __restrict__ logits,
                                                      unsigned* __restrict__ lbf, int N) {
    int i = blockIdx.x * blockDim.x + threadIdx.x;
    int stride = gridDim.x * blockDim.x;
    int total = N << 5;            // N * C2P
    const float2* l2 = (const float2*)logits;
    for (; i < total; i += stride) {
        int node = i >> 5;
        int c = i & 31;
        unsigned v = 0;
        if (c < C2) {
            float2 lv = l2[node * C2 + c];
            v = f2bf(lv.x) | (f2bf(lv.y) << 16);
        }
        lbf[i] = v;
    }
}

// ---------------- Fused pull SpMM + combine (bf16 gather, unroll x4) -------

__global__ __launch_bounds__(256) void spmm_bf_kernel(
    const unsigned* __restrict__ lbf, const float* __restrict__ init,
    const int* __restrict__ offs, const int2* __restrict__ epack,
    unsigned* __restrict__ obf, float* __restrict__ of32, int n, int final_f32) {
    int t = threadIdx.x;
    if (t >= NPB * C2) return;
    int node = blockIdx.x * NPB + t / C2;
    if (node >= n) return;
    int c = t % C2;
    int beg = offs[node], end = offs[node + 1];
    float ax0 = 0.f, ay0 = 0.f, ax1 = 0.f, ay1 = 0.f;
    int k = beg;
    for (; k + 4 <= end; k += 4) {
        int2 e0 = epack[k];
        int2 e1 = epack[k + 1];
        int2 e2 = epack[k + 2];
        int2 e3 = epack[k + 3];
        unsigned u0 = lbf[(e0.x << 5) + c];
        unsigned u1 = lbf[(e1.x << 5) + c];
        unsigned u2 = lbf[(e2.x << 5) + c];
        unsigned u3 = lbf[(e3.x << 5) + c];
        float v0 = __int_as_float(e0.y);
        float v1 = __int_as_float(e1.y);
        float v2 = __int_as_float(e2.y);
        float v3 = __int_as_float(e3.y);
        ax0 = fmaf(v0, __uint_as_float(u0 << 16), ax0);
        ay0 = fmaf(v0, __uint_as_float(u0 & 0xffff0000u), ay0);
        ax1 = fmaf(v1, __uint_as_float(u1 << 16), ax1);
        ay1 = fmaf(v1, __uint_as_float(u1 & 0xffff0000u), ay1);
        ax0 = fmaf(v2, __uint_as_float(u2 << 16), ax0);
        ay0 = fmaf(v2, __uint_as_float(u2 & 0xffff0000u), ay0);
        ax1 = fmaf(v3, __uint_as_float(u3 << 16), ax1);
        ay1 = fmaf(v3, __uint_as_float(u3 & 0xffff0000u), ay1);
    }
    for (; k < end; ++k) {
        int2 e = epack[k];
        unsigned u = lbf[(e.x << 5) + c];
        float v = __int_as_float(e.y);
        ax0 = fmaf(v, __uint_as_float(u << 16), ax0);
        ay0 = fmaf(v, __uint_as_float(u & 0xffff0000u), ay0);
    }
    float ax = ax0 + ax1, ay = ay0 + ay1;
    float2 iv = ((const float2*)init)[node * C2 + c];
    float ox = ALPHA * iv.x + (1.0f - ALPHA) * ax;
    float oy = ALPHA * iv.y + (1.0f - ALPHA) * ay;
    if (final_f32) {
        float2 o; o.x = ox; o.y = oy;
        ((float2*)of32)[node * C2 + c] = o;
    } else {
        obf[(node << 5) + c] = f2bf(ox) | (f2bf(oy) << 16);
    }
}

// ---------------- Fallback (atomic path) ----------------

__global__ void zero_f32(float* __restrict__ p, int n) {
    int i = blockIdx.x * blockDim.x + threadIdx.x;
    int stride = gridDim.x * blockDim.x;
    for (; i < n; i += stride) p[i] = 0.0f;
}

__global__ __launch_bounds__(256) void scatter_kernel(
    const float* __restrict__ l, const int* __restrict__ rows,
    const int* __restrict__ cols, const float* __restrict__ vals,
    float* __restrict__ agg, int E) {
    long long gid = (long long)blockIdx.x * blockDim.x + threadIdx.x;
    int e = (int)(gid >> 6);
    if (e >= E) return;
    int c = (int)(gid & 63);
    if (c >= NCLASS) return;
    float m = vals[e] * l[(long long)cols[e] * NCLASS + c];
    atomicAdd(&agg[(long long)rows[e] * NCLASS + c], m);
}

__global__ void combine_kernel(const float* __restrict__ init,
                               const float* __restrict__ agg,
                               float* __restrict__ out, int n) {
    int i = blockIdx.x * blockDim.x + threadIdx.x;
    int stride = gridDim.x * blockDim.x;
    for (; i < n; i += stride)
        out[i] = ALPHA * init[i] + (1.0f - ALPHA) * agg[i];
}

// ---------------- Launch ----------------

static inline size_t align_up(size_t x, size_t a) { return (x + a - 1) & ~(a - 1); }

extern "C" void kernel_launch(void* const* d_in, const int* in_sizes, int n_in,
                              void* d_out, int out_size, void* d_ws, size_t ws_size,
                              hipStream_t stream) {
    const float* logits = (const float*)d_in[0];
    const int*   rows   = (const int*)d_in[1];
    const int*   cols   = (const int*)d_in[2];
    const float* vals   = (const float*)d_in[3];
    float* out = (float*)d_out;

    const int E  = in_sizes[1];
    const int NC = out_size;
    const int N  = NC / NCLASS;

    const int NBPB = NB * PB;

    // ws layout; lbf_b aliases recbuf (recbuf dead after bucket_csr,
    // lbf_b first written by spmm iteration 0 which runs after it).
    size_t rec_bytes  = (size_t)E * 8;
    size_t lbf_bytes  = (size_t)N * C2P * 4;
    size_t shared_sz  = rec_bytes > lbf_bytes ? rec_bytes : lbf_bytes;

    size_t off_bh     = 0;
    size_t off_bs     = align_up(off_bh   + (size_t)(NBPB + 1) * 4, 256);
    size_t off_offs   = align_up(off_bs   + (size_t)256 * 4,        256);
    size_t off_shared = align_up(off_offs + (size_t)(N + 1) * 4,    256);
    size_t off_epack  = align_up(off_shared + shared_sz,            256);
    size_t off_lbfa   = align_up(off_epack  + (size_t)E * 8,        256);
    size_t need       = off_lbfa + lbf_bytes;

    bool fits = (N <= (NB << RBSH)) && (N <= (1 << 17)) && (ws_size >= need);

    if (fits) {
        char* ws = (char*)d_ws;
        int*      bh     = (int*)     (ws + off_bh);
        int*      bs     = (int*)     (ws + off_bs);
        int*      offs   = (int*)     (ws + off_offs);
        int2*     recbuf = (int2*)    (ws + off_shared);
        unsigned* lbf_b  = (unsigned*)(ws + off_shared);
        int2*     epack  = (int2*)    (ws + off_epack);
        unsigned* lbf_a  = (unsigned*)(ws + off_lbfa);

        int nbuckets = (N + (1 << RBSH) - 1) >> RBSH;

        part_hist<<<PB, 256, 0, stream>>>(rows, bh, E);
        reduce_chunk<<<256, 256, 0, stream>>>(bh, bs, NBPB);
        scan_blocksums<<<1, 256, 0, stream>>>(bs);
        scan_chunk<<<256, 256, 0, stream>>>(bh, bs, bh, NBPB, E);
        part_scatter<<<PB, 256, 0, stream>>>(rows, cols, vals, bh, recbuf, E);
        bucket_csr<<<nbuckets, 256, 0, stream>>>(recbuf, bh, offs, epack, N, E);
        to_bf16_kernel<<<2048, 256, 0, stream>>>(logits, lbf_a, N);

        int sblocks = (N + NPB - 1) / NPB;
        // ping-pong: a->b, b->a, a->b, b->a, a->d_out(f32)
        unsigned* cur = lbf_a;
        unsigned* nxt = lbf_b;
        for (int it = 0; it < NPROP; ++it) {
            int fin = (it == NPROP - 1);
            spmm_bf_kernel<<<sblocks, 256, 0, stream>>>(
                cur, logits, offs, epack, nxt, out, N, fin);
            unsigned* tmp = cur; cur = nxt; nxt = tmp;
        }
    } else {
        // Fallback: atomic scatter path (needs only NC floats of ws)
        float* agg = (float*)d_ws;
        long long sthreads = (long long)E * 64;
        int sblocks = (int)((sthreads + 255) / 256);
        int cblocks = (NC + 255) / 256;
        const float* cur = logits;
        for (int it = 0; it < NPROP; ++it) {
            zero_f32<<<2048, 256, 0, stream>>>(agg, NC);
            scatter_kernel<<<sblocks, 256, 0, stream>>>(cur, rows, cols, vals, agg, E);
            combine_kernel<<<cblocks, 256, 0, stream>>>(logits, agg, out, NC);
            cur = out;
        }
    }
}